// Round 1
// baseline (2748.022 us; speedup 1.0000x reference)
//
#include <hip/hip_runtime.h>

#define N_NODES 100000
#define N_EDGES 3200000
#define N_GRAPHS 512
#define F_IN 128
#define F_HID 64
#define F_CAT 192
#define F_OUT 10

// ---------------------------------------------------------------- degree ----
__global__ void deg_kernel(const int* __restrict__ col, float* __restrict__ deg) {
    int e = blockIdx.x * blockDim.x + threadIdx.x;
    if (e < N_EDGES) atomicAdd(&deg[col[e]], 1.0f);
}

__global__ void dinv_kernel(float* __restrict__ deg) {
    int i = blockIdx.x * blockDim.x + threadIdx.x;
    if (i < N_NODES) {
        float d = deg[i];
        // deg is an integer count; deg>0 => deg>=1 so max(d,1)=d
        deg[i] = d > 0.0f ? rsqrtf(d) : 0.0f;
    }
}

// ------------------------------------------------------------------ GEMM ----
// H[N,64] = X[N,K] @ W[K,64].  W staged fully in LDS, 16 rows of X per block.
template <int K>
__global__ void gemm_kernel(const float* __restrict__ X, const float* __restrict__ W,
                            float* __restrict__ H) {
    __shared__ float Ws[K][64];
    __shared__ float Xs[16][K];
    int tid = threadIdx.x;  // 256 threads
    for (int i = tid; i < K * 64; i += 256) Ws[i / 64][i % 64] = W[i];
    int row0 = blockIdx.x * 16;
    for (int i = tid; i < 16 * K; i += 256) {
        int r = i / K, k = i % K;
        int gr = row0 + r;
        Xs[r][k] = (gr < N_NODES) ? X[(long long)gr * K + k] : 0.0f;
    }
    __syncthreads();
    int c = tid & 63;   // output column
    int rs = tid >> 6;  // 0..3 row sub-group (uniform per wave)
    for (int r = rs; r < 16; r += 4) {
        float acc = 0.0f;
#pragma unroll
        for (int k = 0; k < K; ++k) acc += Xs[r][k] * Ws[k][c];
        int gr = row0 + r;
        if (gr < N_NODES) H[gr * 64 + c] = acc;
    }
}

// --------------------------------------------------------------- scatter ----
// out[col[e]][c] += H[row[e]][c] * dinv[row]*dinv[col];  one lane per (e,c).
__global__ void scatter_kernel(const int* __restrict__ row, const int* __restrict__ col,
                               const float* __restrict__ dinv, const float* __restrict__ H,
                               float* __restrict__ out) {
    int gid = blockIdx.x * blockDim.x + threadIdx.x;  // < E*64 = 204.8M < 2^31
    if (gid >= N_EDGES * 64) return;
    int e = gid >> 6;
    int c = gid & 63;
    int r = row[e];
    int t = col[e];
    float nrm = dinv[r] * dinv[t];
    atomicAdd(&out[t * 64 + c], H[r * 64 + c] * nrm);
}

// ------------------------------------------------------------- bias+relu ----
__global__ void bias_relu_kernel(float* __restrict__ x, const float* __restrict__ b) {
    int gid = blockIdx.x * blockDim.x + threadIdx.x;
    if (gid < N_NODES * 64) {
        float v = x[gid] + b[gid & 63];
        x[gid] = v > 0.0f ? v : 0.0f;
    }
}

// ------------------------------------------------------------------ pool ----
__global__ void pool_kernel(const float* __restrict__ x1, const float* __restrict__ x2,
                            const float* __restrict__ x3, const int* __restrict__ batch,
                            float* __restrict__ pooled, float* __restrict__ cnt) {
    int gid = blockIdx.x * blockDim.x + threadIdx.x;  // N*192 = 19.2M
    if (gid >= N_NODES * F_CAT) return;
    int i = gid / F_CAT;
    int c = gid - i * F_CAT;
    const float* src = (c < 64) ? x1 : ((c < 128) ? x2 : x3);
    float v = src[i * 64 + (c & 63)];
    int g = batch[i];
    atomicAdd(&pooled[g * F_CAT + c], v);
    if (c == 0) atomicAdd(&cnt[g], 1.0f);
}

// ------------------------------------------------------------------ head ----
__global__ void head_kernel(const float* __restrict__ pooled, const float* __restrict__ cnt,
                            const float* __restrict__ Wf, const float* __restrict__ bf,
                            float* __restrict__ out) {
    __shared__ float p[F_CAT];
    __shared__ float logits[F_OUT];
    int g = blockIdx.x;
    int tid = threadIdx.x;  // 64
    float invc = 1.0f / fmaxf(cnt[g], 1.0f);
    for (int i = tid; i < F_CAT; i += 64) p[i] = pooled[g * F_CAT + i] * invc;
    __syncthreads();
    if (tid < F_OUT) {
        float acc = bf[tid];
        for (int k = 0; k < F_CAT; ++k) acc += p[k] * Wf[k * F_OUT + tid];
        logits[tid] = acc;
    }
    __syncthreads();
    if (tid == 0) {
        float m = -1e30f;
        for (int j = 0; j < F_OUT; ++j) m = fmaxf(m, logits[j]);
        float s = 0.0f;
        float ex[F_OUT];
        for (int j = 0; j < F_OUT; ++j) { ex[j] = __expf(logits[j] - m); s += ex[j]; }
        float inv = 1.0f / s;
        for (int j = 0; j < F_OUT; ++j) out[g * F_OUT + j] = ex[j] * inv;
    }
}

// ---------------------------------------------------------------- launch ----
extern "C" void kernel_launch(void* const* d_in, const int* in_sizes, int n_in,
                              void* d_out, int out_size, void* d_ws, size_t ws_size,
                              hipStream_t stream) {
    const float* X0 = (const float*)d_in[0];
    const int* ei = (const int*)d_in[1];
    const int* batch = (const int*)d_in[2];
    const float* W1 = (const float*)d_in[3];
    const float* b1 = (const float*)d_in[4];
    const float* W2 = (const float*)d_in[5];
    const float* b2 = (const float*)d_in[6];
    const float* W3 = (const float*)d_in[7];
    const float* b3 = (const float*)d_in[8];
    const float* Wf = (const float*)d_in[9];
    const float* bf = (const float*)d_in[10];
    float* out = (float*)d_out;

    const int* row = ei;
    const int* col = ei + N_EDGES;

    // workspace layout (floats)
    float* ws = (float*)d_ws;
    float* h = ws;                        // N*64
    float* dinv = h + (size_t)N_NODES * 64;
    float* x1 = dinv + N_NODES;           // N*64, must start zeroed
    float* x2 = x1 + (size_t)N_NODES * 64;
    float* x3 = x2 + (size_t)N_NODES * 64;
    float* pooled = x3 + (size_t)N_NODES * 64;  // 512*192
    float* cnt = pooled + (size_t)N_GRAPHS * F_CAT;

    // zero: dinv .. cnt (contiguous)
    size_t zero_bytes =
        ((size_t)N_NODES + 3ull * N_NODES * 64 + (size_t)N_GRAPHS * F_CAT + N_GRAPHS) * 4;
    hipMemsetAsync(dinv, 0, zero_bytes, stream);

    deg_kernel<<<(N_EDGES + 255) / 256, 256, 0, stream>>>(col, dinv);
    dinv_kernel<<<(N_NODES + 255) / 256, 256, 0, stream>>>(dinv);

    const int gemm_blocks = (N_NODES + 15) / 16;
    const int scat_blocks = (N_EDGES * 64) / 256;  // exact: 3.2M*64 divisible by 256
    const int br_blocks = (N_NODES * 64 + 255) / 256;

    // layer 1
    gemm_kernel<128><<<gemm_blocks, 256, 0, stream>>>(X0, W1, h);
    scatter_kernel<<<scat_blocks, 256, 0, stream>>>(row, col, dinv, h, x1);
    bias_relu_kernel<<<br_blocks, 256, 0, stream>>>(x1, b1);
    // layer 2
    gemm_kernel<64><<<gemm_blocks, 256, 0, stream>>>(x1, W2, h);
    scatter_kernel<<<scat_blocks, 256, 0, stream>>>(row, col, dinv, h, x2);
    bias_relu_kernel<<<br_blocks, 256, 0, stream>>>(x2, b2);
    // layer 3
    gemm_kernel<64><<<gemm_blocks, 256, 0, stream>>>(x2, W3, h);
    scatter_kernel<<<scat_blocks, 256, 0, stream>>>(row, col, dinv, h, x3);
    bias_relu_kernel<<<br_blocks, 256, 0, stream>>>(x3, b3);
    // pool + head
    pool_kernel<<<(N_NODES * F_CAT + 255) / 256, 256, 0, stream>>>(x1, x2, x3, batch, pooled, cnt);
    head_kernel<<<N_GRAPHS, 64, 0, stream>>>(pooled, cnt, Wf, bf, out);
}

// Round 2
// 1191.388 us; speedup vs baseline: 2.3066x; 2.3066x over previous
//
#include <hip/hip_runtime.h>

#define N_NODES 100000
#define N_EDGES 3200000
#define N_GRAPHS 512
#define F_IN 128
#define F_HID 64
#define F_CAT 192
#define F_OUT 10

// ------------------------------------------------------------- histogram ----
__global__ void deg_kernel(const int* __restrict__ col, int* __restrict__ cnt) {
    int e = blockIdx.x * blockDim.x + threadIdx.x;
    if (e < N_EDGES) atomicAdd(&cnt[col[e]], 1);
}

__global__ void dinv_kernel(const int* __restrict__ cnt, float* __restrict__ dinv) {
    int i = blockIdx.x * blockDim.x + threadIdx.x;
    if (i < N_NODES) {
        int d = cnt[i];
        dinv[i] = d > 0 ? rsqrtf((float)d) : 0.0f;
    }
}

// ------------------------------------------------- two-level prefix scan ----
// scan1: per-block (256) exclusive scan of cnt -> start, block totals -> bsum
__global__ void scan1_kernel(const int* __restrict__ cnt, int* __restrict__ start,
                             int* __restrict__ bsum) {
    __shared__ int s[256];
    int t = threadIdx.x;
    int i = blockIdx.x * 256 + t;
    int v = (i < N_NODES) ? cnt[i] : 0;
    s[t] = v;
    __syncthreads();
    for (int o = 1; o < 256; o <<= 1) {
        int x = (t >= o) ? s[t - o] : 0;
        __syncthreads();
        s[t] += x;
        __syncthreads();
    }
    if (i < N_NODES) start[i] = s[t] - v;  // exclusive within block
    if (t == 255) bsum[blockIdx.x] = s[255];
}

// scan2: single block scans the 391 block sums -> exclusive offsets
__global__ void scan2_kernel(int* __restrict__ bsum, int nblk) {
    __shared__ int s[512];
    int t = threadIdx.x;  // 512
    int v = (t < nblk) ? bsum[t] : 0;
    s[t] = v;
    __syncthreads();
    for (int o = 1; o < 512; o <<= 1) {
        int x = (t >= o) ? s[t - o] : 0;
        __syncthreads();
        s[t] += x;
        __syncthreads();
    }
    if (t < nblk) bsum[t] = s[t] - v;  // exclusive
}

// scan3: add block offsets; also write the sentinel start[N] = E
__global__ void scan3_kernel(int* __restrict__ start, const int* __restrict__ bsum) {
    int i = blockIdx.x * blockDim.x + threadIdx.x;
    if (i < N_NODES) start[i] += bsum[i >> 8];
    if (i == 0) start[N_NODES] = N_EDGES;
}

// ------------------------------------------------------- CSC placement -----
__global__ void place_kernel(const int* __restrict__ row, const int* __restrict__ col,
                             const int* __restrict__ start, int* __restrict__ cursor,
                             int* __restrict__ csr_row) {
    int e = blockIdx.x * blockDim.x + threadIdx.x;
    if (e < N_EDGES) {
        int d = col[e];
        int ofs = atomicAdd(&cursor[d], 1);
        csr_row[start[d] + ofs] = row[e];
    }
}

// ------------------------------------------------------------------ GEMM ----
// HP[N,64] = (X[N,K] @ W[K,64]) * dinv[node].  W fully in LDS; 16 X-rows/block.
template <int K>
__global__ void gemm_kernel(const float* __restrict__ X, const float* __restrict__ W,
                            const float* __restrict__ dinv, float* __restrict__ HP) {
    __shared__ float Ws[K][64];
    __shared__ float Xs[16][K];
    int tid = threadIdx.x;  // 256
    for (int i = tid; i < K * 64; i += 256) Ws[i / 64][i % 64] = W[i];
    int row0 = blockIdx.x * 16;
    for (int i = tid; i < 16 * K; i += 256) {
        int r = i / K, k = i % K;
        int gr = row0 + r;
        Xs[r][k] = (gr < N_NODES) ? X[(long long)gr * K + k] : 0.0f;
    }
    __syncthreads();
    int c = tid & 63;
    int rs = tid >> 6;
    for (int r = rs; r < 16; r += 4) {
        float acc = 0.0f;
#pragma unroll
        for (int k = 0; k < K; ++k) acc += Xs[r][k] * Ws[k][c];
        int gr = row0 + r;
        if (gr < N_NODES) HP[gr * 64 + c] = acc * dinv[gr];
    }
}

// ------------------------------------------------------------- aggregate ----
// out[i][c] = relu(dinv[i] * sum_{j in seg(i)} hp[csr_row[j]][c] + b[c])
// fused: pooled[batch[i]*192 + POFF + c] += out  (+ node count on layer 1)
template <bool WRITE, bool COUNT, int POFF>
__global__ void aggregate_kernel(const int* __restrict__ csr_row, const int* __restrict__ start,
                                 const float* __restrict__ hp, const float* __restrict__ dinv,
                                 const float* __restrict__ b, float* __restrict__ out,
                                 const int* __restrict__ batch, float* __restrict__ pooled,
                                 float* __restrict__ cntg) {
    int node = blockIdx.x * 4 + (threadIdx.x >> 6);
    if (node >= N_NODES) return;
    int c = threadIdx.x & 63;
    int s0 = start[node], s1 = start[node + 1];
    float acc = 0.0f;
    int j = s0;
    for (; j + 3 < s1; j += 4) {
        int r0 = csr_row[j];
        int r1 = csr_row[j + 1];
        int r2 = csr_row[j + 2];
        int r3 = csr_row[j + 3];
        float v0 = hp[r0 * 64 + c];
        float v1 = hp[r1 * 64 + c];
        float v2 = hp[r2 * 64 + c];
        float v3 = hp[r3 * 64 + c];
        acc += v0 + v1 + v2 + v3;
    }
    for (; j < s1; ++j) acc += hp[csr_row[j] * 64 + c];
    float v = fmaxf(dinv[node] * acc + b[c], 0.0f);
    if (WRITE) out[node * 64 + c] = v;
    int g = batch[node];
    atomicAdd(&pooled[g * F_CAT + POFF + c], v);
    if (COUNT && c == 0) atomicAdd(&cntg[g], 1.0f);
}

// ------------------------------------------------------------------ head ----
__global__ void head_kernel(const float* __restrict__ pooled, const float* __restrict__ cnt,
                            const float* __restrict__ Wf, const float* __restrict__ bf,
                            float* __restrict__ out) {
    __shared__ float p[F_CAT];
    __shared__ float logits[F_OUT];
    int g = blockIdx.x;
    int tid = threadIdx.x;  // 64
    float invc = 1.0f / fmaxf(cnt[g], 1.0f);
    for (int i = tid; i < F_CAT; i += 64) p[i] = pooled[g * F_CAT + i] * invc;
    __syncthreads();
    if (tid < F_OUT) {
        float acc = bf[tid];
        for (int k = 0; k < F_CAT; ++k) acc += p[k] * Wf[k * F_OUT + tid];
        logits[tid] = acc;
    }
    __syncthreads();
    if (tid == 0) {
        float m = -1e30f;
        for (int j = 0; j < F_OUT; ++j) m = fmaxf(m, logits[j]);
        float s = 0.0f;
        float ex[F_OUT];
        for (int j = 0; j < F_OUT; ++j) { ex[j] = __expf(logits[j] - m); s += ex[j]; }
        float inv = 1.0f / s;
        for (int j = 0; j < F_OUT; ++j) out[g * F_OUT + j] = ex[j] * inv;
    }
}

// ---------------------------------------------------------------- launch ----
extern "C" void kernel_launch(void* const* d_in, const int* in_sizes, int n_in,
                              void* d_out, int out_size, void* d_ws, size_t ws_size,
                              hipStream_t stream) {
    const float* X0 = (const float*)d_in[0];
    const int* ei = (const int*)d_in[1];
    const int* batch = (const int*)d_in[2];
    const float* W1 = (const float*)d_in[3];
    const float* b1 = (const float*)d_in[4];
    const float* W2 = (const float*)d_in[5];
    const float* b2 = (const float*)d_in[6];
    const float* W3 = (const float*)d_in[7];
    const float* b3 = (const float*)d_in[8];
    const float* Wf = (const float*)d_in[9];
    const float* bf = (const float*)d_in[10];
    float* out = (float*)d_out;

    const int* row = ei;
    const int* col = ei + N_EDGES;

    const int SCAN_BLOCKS = (N_NODES + 255) / 256;  // 391

    // ---- workspace layout (4-byte elements) ----
    // zeroed region first: cnt_i | cursor | pooled | cntg
    char* wp = (char*)d_ws;
    int* cnt_i = (int*)wp;                 wp += (size_t)N_NODES * 4;
    int* cursor = (int*)wp;                wp += (size_t)N_NODES * 4;
    float* pooled = (float*)wp;            wp += (size_t)N_GRAPHS * F_CAT * 4;
    float* cntg = (float*)wp;              wp += (size_t)N_GRAPHS * 4;
    size_t zero_bytes = (size_t)(wp - (char*)d_ws);
    // non-zeroed:
    float* dinv = (float*)wp;              wp += (size_t)N_NODES * 4;
    int* start = (int*)wp;                 wp += (size_t)(N_NODES + 1) * 4;
    int* bsum = (int*)wp;                  wp += (size_t)512 * 4;
    int* csr_row = (int*)wp;               wp += (size_t)N_EDGES * 4;
    float* h = (float*)wp;                 wp += (size_t)N_NODES * 64 * 4;
    float* x1 = (float*)wp;                wp += (size_t)N_NODES * 64 * 4;
    float* x2 = (float*)wp;                wp += (size_t)N_NODES * 64 * 4;

    hipMemsetAsync(d_ws, 0, zero_bytes, stream);

    // ---- graph preprocessing: degrees, dinv, CSC build ----
    deg_kernel<<<(N_EDGES + 255) / 256, 256, 0, stream>>>(col, cnt_i);
    dinv_kernel<<<(N_NODES + 255) / 256, 256, 0, stream>>>(cnt_i, dinv);
    scan1_kernel<<<SCAN_BLOCKS, 256, 0, stream>>>(cnt_i, start, bsum);
    scan2_kernel<<<1, 512, 0, stream>>>(bsum, SCAN_BLOCKS);
    scan3_kernel<<<(N_NODES + 255) / 256, 256, 0, stream>>>(start, bsum);
    place_kernel<<<(N_EDGES + 255) / 256, 256, 0, stream>>>(row, col, start, cursor, csr_row);

    const int gemm_blocks = (N_NODES + 15) / 16;
    const int agg_blocks = (N_NODES + 3) / 4;

    // ---- layer 1 ----
    gemm_kernel<128><<<gemm_blocks, 256, 0, stream>>>(X0, W1, dinv, h);
    aggregate_kernel<true, true, 0><<<agg_blocks, 256, 0, stream>>>(
        csr_row, start, h, dinv, b1, x1, batch, pooled, cntg);
    // ---- layer 2 ----
    gemm_kernel<64><<<gemm_blocks, 256, 0, stream>>>(x1, W2, dinv, h);
    aggregate_kernel<true, false, 64><<<agg_blocks, 256, 0, stream>>>(
        csr_row, start, h, dinv, b2, x2, batch, pooled, cntg);
    // ---- layer 3 ----
    gemm_kernel<64><<<gemm_blocks, 256, 0, stream>>>(x2, W3, dinv, h);
    aggregate_kernel<false, false, 128><<<agg_blocks, 256, 0, stream>>>(
        csr_row, start, h, dinv, b3, nullptr, batch, pooled, cntg);
    // ---- head ----
    head_kernel<<<N_GRAPHS, 64, 0, stream>>>(pooled, cntg, Wf, bf, out);
}